// Round 1
// baseline (22326.237 us; speedup 1.0000x reference)
//
#include <hip/hip_runtime.h>

typedef float v4 __attribute__((ext_vector_type(4)));

#define ROWF 12                    // floats per padded row (16B-aligned rows)
#define CHF  96                    // floats per channel slot: 8 rows x 12
#define BASE 12                    // leading zero row
#define NSLOT 384
#define MISCOFF (BASE + NSLOT*CHF) // 36876: fc partial sums 8*64
#define PREDOFF (MISCOFF + 512)
#define SHF (PREDOFF + 4)          // 37392 floats = 149568 B

// LDS slot map:
//  phase A: x: 0..255, conv0 out: 256..383
//  recurrent: x_feat: 0..127, v_p2:128, v_p1:129, v_first:130, h0:131..194, h1:195..258
// Channel slot layout: base=BASE+slot*CHF; image row r (0..6) at base+r*ROWF, real col c at +1+c.
// Row 7 of each slot is a zero row; row -1 = previous slot's row 7 (zero) => branch-free SAME conv.

__device__ __forceinline__ float sigmoidf_(float v) { return 1.0f / (1.0f + expf(-v)); }

__device__ __forceinline__ void load_row12(const float* rb, float* rr) {
    v4 t0 = *(const v4*)(rb);
    v4 t1 = *(const v4*)(rb + 4);
    v4 t2 = *(const v4*)(rb + 8);
    rr[0] = t0[0]; rr[1] = t0[1]; rr[2]  = t0[2]; rr[3]  = t0[3];
    rr[4] = t1[0]; rr[5] = t1[1]; rr[6]  = t1[2]; rr[7]  = t1[3];
    rr[8] = t2[0]; rr[9] = t2[1]; rr[10] = t2[2]; rr[11] = t2[3];
}

// gates conv: thread owns hidden channel c (4 gate out-channels c, 64+c, 128+c, 192+c),
// one output row. Weights: v4 per (ic,tap): [ic][tap][c][4g].
__device__ __forceinline__ void conv_gates(const float* SH, const v4* wbase, int nic,
                                           int slot0, int row,
                                           float* a0, float* a1, float* a2, float* a3)
{
    for (int ic = 0; ic < nic; ++ic) {
        const float* rb = &SH[BASE + (slot0 + ic) * CHF + (row - 1) * ROWF];
        float rr0[12], rr1[12], rr2[12];
        load_row12(rb, rr0);
        load_row12(rb + ROWF, rr1);
        load_row12(rb + 2 * ROWF, rr2);
        const v4* wp = wbase + (size_t)ic * 576;   // 9 taps * 64 v4
        #pragma unroll
        for (int dy = 0; dy < 3; ++dy) {
            const float* rr = (dy == 0) ? rr0 : (dy == 1) ? rr1 : rr2;
            #pragma unroll
            for (int dx = 0; dx < 3; ++dx) {
                v4 w = wp[(dy * 3 + dx) * 64];
                #pragma unroll
                for (int cc = 0; cc < 7; ++cc) {
                    float in = rr[cc + dx];
                    a0[cc] = fmaf(w[0], in, a0[cc]);
                    a1[cc] = fmaf(w[1], in, a1[cc]);
                    a2[cc] = fmaf(w[2], in, a2[cc]);
                    a3[cc] = fmaf(w[3], in, a3[cc]);
                }
            }
        }
    }
}

// feature conv: thread owns out-channel oc, two output rows r0, r0+1. Weights [ic][tap][OC].
__device__ __forceinline__ void conv_feat(const float* SH, const float* w, int nic,
                                          int slot0, int oc, int OC, int r0,
                                          float* a0, float* a1)
{
    for (int ic = 0; ic < nic; ++ic) {
        const float* rb = &SH[BASE + (slot0 + ic) * CHF + (r0 - 1) * ROWF];
        float rr0[12], rr1[12], rr2[12], rr3[12];
        load_row12(rb, rr0);
        load_row12(rb + ROWF, rr1);
        load_row12(rb + 2 * ROWF, rr2);
        load_row12(rb + 3 * ROWF, rr3);   // row r0+2; junk for r0==6 (discarded)
        const float* wp = w + (size_t)ic * 9 * OC + oc;
        #pragma unroll
        for (int dy = 0; dy < 3; ++dy) {
            const float* ra = (dy == 0) ? rr0 : (dy == 1) ? rr1 : rr2;
            const float* rb2 = (dy == 0) ? rr1 : (dy == 1) ? rr2 : rr3;
            #pragma unroll
            for (int dx = 0; dx < 3; ++dx) {
                float wv = wp[(dy * 3 + dx) * OC];
                #pragma unroll
                for (int cc = 0; cc < 7; ++cc) {
                    a0[cc] = fmaf(wv, ra[cc + dx], a0[cc]);
                    a1[cc] = fmaf(wv, rb2[cc + dx], a1[cc]);
                }
            }
        }
    }
}

extern "C" __global__ __launch_bounds__(512)
void poly_rnn_main(const float* __restrict__ x,
                   const int*   __restrict__ firstv,
                   const float* __restrict__ w_c0, const float* __restrict__ b_c0,
                   const float* __restrict__ w_c1, const float* __restrict__ b_c1,
                   const float* __restrict__ w_g0,
                   const float* __restrict__ cx0b, const float* __restrict__ ch0b,
                   const float* __restrict__ w_g1,
                   const float* __restrict__ cx1b, const float* __restrict__ ch1b,
                   const float* __restrict__ fcw,  const float* __restrict__ fcb,
                   float* __restrict__ out)
{
    extern __shared__ float SH[];
    const int tid = threadIdx.x;
    const int s = blockIdx.x;

    for (int i = tid; i < SHF; i += 512) SH[i] = 0.f;
    __syncthreads();

    // stage x sample into slots 0..255 (padded layout)
    const float* xs = x + (size_t)s * (256 * 49);
    for (int i = tid; i < 256 * 49; i += 512) {
        int ch = i / 49, p = i % 49;
        SH[BASE + ch * CHF + (p / 7) * ROWF + 1 + (p % 7)] = xs[i];
    }
    __syncthreads();

    // ---- conv0 + relu: slots 0..255 -> 256..383 ----
    {
        const int oc = tid & 127, pg = tid >> 7;   // wave-uniform pg
        const int r0 = 2 * pg;
        float a0[7] = {0,0,0,0,0,0,0}, a1[7] = {0,0,0,0,0,0,0};
        conv_feat(SH, w_c0, 256, 0, oc, 128, r0, a0, a1);
        float b = b_c0[oc];
        float* ob = &SH[BASE + (256 + oc) * CHF];
        #pragma unroll
        for (int cc = 0; cc < 7; ++cc) ob[r0 * ROWF + 1 + cc] = fmaxf(a0[cc] + b, 0.f);
        if (pg < 3) {
            #pragma unroll
            for (int cc = 0; cc < 7; ++cc) ob[(r0 + 1) * ROWF + 1 + cc] = fmaxf(a1[cc] + b, 0.f);
        }
    }
    __syncthreads();

    // ---- conv1 + relu: slots 256..383 -> 0..127 (x_feat) ----
    {
        const int oc = tid & 127, pg = tid >> 7;
        const int r0 = 2 * pg;
        float a0[7] = {0,0,0,0,0,0,0}, a1[7] = {0,0,0,0,0,0,0};
        conv_feat(SH, w_c1, 128, 256, oc, 128, r0, a0, a1);
        float b = b_c1[oc];
        float* ob = &SH[BASE + oc * CHF];
        #pragma unroll
        for (int cc = 0; cc < 7; ++cc) ob[r0 * ROWF + 1 + cc] = fmaxf(a0[cc] + b, 0.f);
        if (pg < 3) {
            #pragma unroll
            for (int cc = 0; cc < 7; ++cc) ob[(r0 + 1) * ROWF + 1 + cc] = fmaxf(a1[cc] + b, 0.f);
        }
    }
    __syncthreads();

    // ---- recurrent init: zero slots 128..258 (v maps, h0, h1) ----
    for (int i = tid; i < 131 * CHF; i += 512) SH[BASE + 128 * CHF + i] = 0.f;
    __syncthreads();
    if (tid == 0) {
        int fv = firstv[s];
        int off = (fv / 7) * ROWF + 1 + (fv % 7);
        SH[BASE + 129 * CHF + off] = 1.f;   // v_p1 = v_first
        SH[BASE + 130 * CHF + off] = 1.f;   // v_first
    }

    const int c = tid & 63, pg = tid >> 6;  // pg == wave id; rows 0..6 active, pg7 idle in convs
    float c0r[7] = {0,0,0,0,0,0,0}, c1r[7] = {0,0,0,0,0,0,0};
    float* outS = out + (size_t)s * (9 * 50);

    const float bi0 = cx0b[c]       + ch0b[c];
    const float bf0 = cx0b[64 + c]  + ch0b[64 + c];
    const float bg0 = cx0b[128 + c] + ch0b[128 + c];
    const float bo0 = cx0b[192 + c] + ch0b[192 + c];
    const float bi1 = cx1b[c]       + ch1b[c];
    const float bf1 = cx1b[64 + c]  + ch1b[64 + c];
    const float bg1 = cx1b[128 + c] + ch1b[128 + c];
    const float bo1 = cx1b[192 + c] + ch1b[192 + c];

    for (int t = 0; t < 9; ++t) {
        __syncthreads();                                   // A: prior v/h writes visible
        float a0[7], a1[7], a2[7], a3[7];
        if (pg < 7) {
            #pragma unroll
            for (int cc = 0; cc < 7; ++cc) { a0[cc] = bi0; a1[cc] = bf0; a2[cc] = bg0; a3[cc] = bo0; }
            conv_gates(SH, ((const v4*)w_g0) + c, 195, 0, pg, a0, a1, a2, a3);
        }
        __syncthreads();                                   // B: done reading h0
        if (pg < 7) {
            float* h0row = &SH[BASE + (131 + c) * CHF + pg * ROWF + 1];
            #pragma unroll
            for (int cc = 0; cc < 7; ++cc) {
                float ig = sigmoidf_(a0[cc]);
                float fg = sigmoidf_(a1[cc]);
                float gg = tanhf(a2[cc]);
                float og = sigmoidf_(a3[cc]);
                float cy = fg * c0r[cc] + ig * gg;
                c0r[cc] = cy;
                h0row[cc] = og * tanhf(cy);
            }
        }
        __syncthreads();                                   // C: h0 visible
        if (pg < 7) {
            #pragma unroll
            for (int cc = 0; cc < 7; ++cc) { a0[cc] = bi1; a1[cc] = bf1; a2[cc] = bg1; a3[cc] = bo1; }
            conv_gates(SH, ((const v4*)w_g1) + c, 128, 131, pg, a0, a1, a2, a3);
        }
        __syncthreads();                                   // D: done reading h1
        if (pg < 7) {
            float* h1row = &SH[BASE + (195 + c) * CHF + pg * ROWF + 1];
            #pragma unroll
            for (int cc = 0; cc < 7; ++cc) {
                float ig = sigmoidf_(a0[cc]);
                float fg = sigmoidf_(a1[cc]);
                float gg = tanhf(a2[cc]);
                float og = sigmoidf_(a3[cc]);
                float cy = fg * c1r[cc] + ig * gg;
                c1r[cc] = cy;
                h1row[cc] = og * tanhf(cy);
            }
        }
        __syncthreads();                                   // E: h1 visible
        // ---- fc partials: lane k = c (k<50 live; fcw zero-padded), wave = c-chunk ----
        {
            float acc = 0.f;
            for (int c8 = 0; c8 < 8; ++c8) {
                int hc = pg * 8 + c8;
                const float* hb = &SH[BASE + (195 + hc) * CHF];
                const float* wb = fcw + (size_t)(hc * 49) * 64 + c;
                #pragma unroll
                for (int r = 0; r < 7; ++r)
                    #pragma unroll
                    for (int cc2 = 0; cc2 < 7; ++cc2)
                        acc = fmaf(hb[r * ROWF + 1 + cc2], wb[(r * 7 + cc2) * 64], acc);
            }
            SH[MISCOFF + pg * 64 + c] = acc;
        }
        __syncthreads();                                   // F: partials visible
        if (tid < 64) {
            float v = -__builtin_inff();
            if (tid < 50) {
                float sum = fcb[tid];
                #pragma unroll
                for (int p2 = 0; p2 < 8; ++p2) sum += SH[MISCOFF + p2 * 64 + tid];
                outS[t * 50 + tid] = sum;
                v = sum;
            }
            int idx = tid;
            #pragma unroll
            for (int off2 = 1; off2 < 64; off2 <<= 1) {
                float ov = __shfl_xor(v, off2, 64);
                int   oi = __shfl_xor(idx, off2, 64);
                if (ov > v || (ov == v && oi < idx)) { v = ov; idx = oi; }
            }
            if (tid == 0) SH[PREDOFF] = (float)idx;        // first-max == jnp.argmax
        }
        __syncthreads();                                   // G: pred visible
        if (tid < 96) {
            int pred = (int)SH[PREDOFF];
            float pv = SH[BASE + 129 * CHF + tid];         // old v_p1
            int oh = (pred / 7) * ROWF + 1 + (pred % 7);
            SH[BASE + 128 * CHF + tid] = pv;               // v_p2 <- v_p1
            SH[BASE + 129 * CHF + tid] = (pred < 49 && tid == oh) ? 1.f : 0.f;
        }
        // loop-top barrier A orders these for the next step
    }
}

// ---------- weight repack kernels ----------
__global__ void repack_conv_k(const float* __restrict__ w, float* __restrict__ o, int IC, int OC) {
    int i = blockIdx.x * 256 + threadIdx.x;
    int total = OC * IC * 9;
    if (i >= total) return;
    int oc = i % OC; int r = i / OC; int t = r % 9; int ic = r / 9;
    o[i] = w[(size_t)(oc * IC + ic) * 9 + t];
}

__global__ void repack_gates_k(const float* __restrict__ wx, const float* __restrict__ wh,
                               float* __restrict__ o, int ICX) {
    int i = blockIdx.x * 256 + threadIdx.x;
    int total = (ICX + 64) * 9 * 256;
    if (i >= total) return;
    int g = i & 3; int r = i >> 2; int cc = r & 63; r >>= 6; int t = r % 9; int ic = r / 9;
    int oc = g * 64 + cc;
    float v = (ic < ICX) ? wx[(size_t)(oc * ICX + ic) * 9 + t]
                         : wh[(size_t)(oc * 64 + (ic - ICX)) * 9 + t];
    o[i] = v;
}

__global__ void repack_fc_k(const float* __restrict__ w, float* __restrict__ o) {
    int i = blockIdx.x * 256 + threadIdx.x;
    if (i >= 3136 * 64) return;
    int k = i & 63; int j = i >> 6;
    o[i] = (k < 50) ? w[(size_t)k * 3136 + j] : 0.f;
}

extern "C" void kernel_launch(void* const* d_in, const int* in_sizes, int n_in,
                              void* d_out, int out_size, void* d_ws, size_t ws_size,
                              hipStream_t stream)
{
    const float* x     = (const float*)d_in[0];
    const int*   fv    = (const int*)  d_in[1];
    const float* c0w   = (const float*)d_in[2];
    const float* c0b   = (const float*)d_in[3];
    const float* c1w   = (const float*)d_in[4];
    const float* c1b   = (const float*)d_in[5];
    const float* cx0w  = (const float*)d_in[6];
    const float* cx0b  = (const float*)d_in[7];
    const float* ch0w  = (const float*)d_in[8];
    const float* ch0b  = (const float*)d_in[9];
    const float* cx1w  = (const float*)d_in[10];
    const float* cx1b  = (const float*)d_in[11];
    const float* ch1w  = (const float*)d_in[12];
    const float* ch1b  = (const float*)d_in[13];
    const float* fcw   = (const float*)d_in[14];
    const float* fcb   = (const float*)d_in[15];
    float* out = (float*)d_out;
    const int n = in_sizes[0] / (256 * 49);

    float* ws   = (float*)d_ws;
    float* w_c0 = ws;               // 256*9*128  = 294912
    float* w_c1 = w_c0 + 294912;    // 128*9*128  = 147456
    float* w_g0 = w_c1 + 147456;    // 195*9*256  = 449280
    float* w_g1 = w_g0 + 449280;    // 128*9*256  = 294912
    float* w_fc = w_g1 + 294912;    // 3136*64    = 200704

    repack_conv_k <<<(294912 + 255) / 256, 256, 0, stream>>>(c0w, w_c0, 256, 128);
    repack_conv_k <<<(147456 + 255) / 256, 256, 0, stream>>>(c1w, w_c1, 128, 128);
    repack_gates_k<<<(449280 + 255) / 256, 256, 0, stream>>>(cx0w, ch0w, w_g0, 131);
    repack_gates_k<<<(294912 + 255) / 256, 256, 0, stream>>>(cx1w, ch1w, w_g1, 64);
    repack_fc_k   <<<(200704 + 255) / 256, 256, 0, stream>>>(fcw, w_fc);

    (void)hipFuncSetAttribute((const void*)poly_rnn_main,
                              hipFuncAttributeMaxDynamicSharedMemorySize, SHF * 4);
    poly_rnn_main<<<n, 512, SHF * 4, stream>>>(x, fv, w_c0, c0b, w_c1, c1b,
                                               w_g0, cx0b, ch0b, w_g1, cx1b, ch1b,
                                               w_fc, fcb, out);
}